// Round 7
// baseline (154.002 us; speedup 1.0000x reference)
//
#include <hip/hip_runtime.h>
#include <hip/hip_bf16.h>
#include <cstdint>
#include <cstddef>

// StreamingAttentionBlock: B=2, T=2048, DIM=1024, H=16, hd=64, window=3 keys
// I/O: fp32. Internal: bf16 MFMA, fp32 accumulation.
// R16: attn FUSED into GEMM2 (attn_gemm2). Rationale: per-kernel floors are
// reached (R14/R15 returned <2us each); the remaining lever is launch-count.
// attn for GEMM2's 64-row A-tile depends only on qkv rows r..r+2 -> block-local.
// Per K-step (BK=128 = 2 heads): thread (row=tid>>3, g8=tid&7) computes 16 attn
// dims (q.k dots reduced via __shfl_xor(1,2) in 4-lane same-head groups, 3-key
// softmax, PV) and ds_writes into the SAME [kh][64][32] LDS layout the proven
// MFMA loop reads. B staged via global_load_lds as before. Single-buffered,
// 2 barriers/K-step: race-free by construction. 512 thr (8 waves 2x4), 48KB LDS.
// Removes: attn dispatch (~10us) + 1 gap + 8MB write + 64MB logical re-read.
// Adds: x8 bn-redundant attn VALU (overlaps MFMA, m114) + ~200MB L2-hot reads.
// prep / GEMM1 byte-identical to R15 (measured floor).
#define T_SEQ 2048
#define NBATCH 2
#define DIMSZ 1024
#define NHEAD 16
#define HDIM 64

typedef float f32x4 __attribute__((ext_vector_type(4)));
typedef short bf16x8 __attribute__((ext_vector_type(8)));

// async global->LDS, 16B per lane. LDS dest = wave-uniform base + lane*16.
__device__ __forceinline__ void gld_lds16(const __hip_bfloat16* g, __hip_bfloat16* l) {
    __builtin_amdgcn_global_load_lds(
        (const __attribute__((address_space(1))) unsigned int*)g,
        (__attribute__((address_space(3))) unsigned int*)l,
        16, 0, 0);
}

__device__ __forceinline__ float bf2f(unsigned short u) {
    union { unsigned int i; float f; } c; c.i = (unsigned int)u << 16; return c.f;
}

// -------- fused prep: convert x -> bf16; convert+transpose both weights --------
// grid: [0,4096) x-convert | [4096,4864) wqkv 64x64 tiles | [4864,5120) wproj
__global__ __launch_bounds__(256) void prep(
    const float* __restrict__ x,      __hip_bfloat16* __restrict__ xb,
    const float* __restrict__ wqkv,   __hip_bfloat16* __restrict__ wqkvT,
    const float* __restrict__ wproj,  __hip_bfloat16* __restrict__ wprojT)
{
    __shared__ float tile[64][65];
    const int b = blockIdx.x;
    if (b < 4096) {
        int i = (b * 256 + threadIdx.x) * 4;
        float4 v = *(const float4*)(x + i);
        union { __hip_bfloat16 h[4]; ushort4 u; } pk;
        pk.h[0] = __hip_bfloat16(v.x); pk.h[1] = __hip_bfloat16(v.y);
        pk.h[2] = __hip_bfloat16(v.z); pk.h[3] = __hip_bfloat16(v.w);
        *(ushort4*)(xb + i) = pk.u;
        return;
    }
    const float* in; __hip_bfloat16* out; int C, c0, r0;
    if (b < 4864) {
        int bb = b - 4096; in = wqkv; out = wqkvT; C = 3072;
        c0 = (bb % 48) * 64; r0 = (bb / 48) * 64;
    } else {
        int bb = b - 4864; in = wproj; out = wprojT; C = 1024;
        c0 = (bb & 15) * 64; r0 = (bb >> 4) * 64;
    }
    const int tx = threadIdx.x & 63, ty = threadIdx.x >> 6;   // 64 lanes x 4 rows
#pragma unroll
    for (int p = 0; p < 16; ++p) {
        int row = ty + p * 4;
        tile[row][tx] = in[(size_t)(r0 + row) * C + c0 + tx];
    }
    __syncthreads();
#pragma unroll
    for (int p = 0; p < 16; ++p) {
        int orow = ty + p * 4;   // out row = c0+orow; out col = r0+tx
        out[(size_t)(c0 + orow) * 1024 + r0 + tx] = __hip_bfloat16(tile[tx][orow]);
    }
}

// -------- GEMM1: 128x128 tile, BK=64 as two m97-style 32-wide sub-tiles --------
__global__ __launch_bounds__(256) void gemm_bt_128(
    const __hip_bfloat16* __restrict__ A,
    const __hip_bfloat16* __restrict__ Bt,
    __hip_bfloat16* __restrict__ C,
    int M, int N, int K)
{
    __shared__ __align__(16) __hip_bfloat16 As[2 * 128 * 32];
    __shared__ __align__(16) __hip_bfloat16 Bs[2 * 128 * 32];

    const int tid  = threadIdx.x;
    const int wv   = tid >> 6;
    const int lane = tid & 63;
    const int bn   = blockIdx.x, bm = blockIdx.y;
    const int wm   = wv >> 1, wn = wv & 1;

    f32x4 acc[4][4] = {};

    const int srow = lane >> 2;          // 0..15
    const int scol = (lane & 3) * 8;     // 16B per lane

    const __hip_bfloat16* Ag = A  + (size_t)(bm * 128) * K;
    const __hip_bfloat16* Bg = Bt + (size_t)(bn * 128) * K;

    const int fm = lane & 15;
    const int fq = (lane >> 4) * 8;

    for (int kk = 0; kk < K; kk += 64) {
#pragma unroll
        for (int kh = 0; kh < 2; ++kh)
#pragma unroll
            for (int it = 0; it < 2; ++it) {
                int row = (it * 4 + wv) * 16 + srow;          // 0..127
                gld_lds16(Ag + (size_t)row * K + kk + kh * 32 + scol,
                          As + kh * 4096 + row * 32 + scol);
                gld_lds16(Bg + (size_t)row * K + kk + kh * 32 + scol,
                          Bs + kh * 4096 + row * 32 + scol);
            }
        __syncthreads();

#pragma unroll
        for (int kh = 0; kh < 2; ++kh) {
            bf16x8 af[4], bfr[4];
#pragma unroll
            for (int i = 0; i < 4; ++i)
                af[i] = *(const bf16x8*)(As + kh * 4096 + (wm * 64 + i * 16 + fm) * 32 + fq);
#pragma unroll
            for (int j = 0; j < 4; ++j)
                bfr[j] = *(const bf16x8*)(Bs + kh * 4096 + (wn * 64 + j * 16 + fm) * 32 + fq);
#pragma unroll
            for (int i = 0; i < 4; ++i)
#pragma unroll
                for (int j = 0; j < 4; ++j)
                    acc[i][j] = __builtin_amdgcn_mfma_f32_16x16x32_bf16(af[i], bfr[j], acc[i][j], 0, 0, 0);
        }
        __syncthreads();
    }

    // C/D layout: col=lane&15, row=(lane>>4)*4+reg  [m89-verified]
    const int fcol  = lane & 15;
    const int frow4 = (lane >> 4) * 4;
    const int cm0 = bm * 128 + wm * 64;
    const int cn0 = bn * 128 + wn * 64;
#pragma unroll
    for (int j = 0; j < 4; ++j) {
        int col = cn0 + j * 16 + fcol;
#pragma unroll
        for (int i = 0; i < 4; ++i)
#pragma unroll
            for (int r = 0; r < 4; ++r) {
                int row = cm0 + i * 16 + frow4 + r;
                C[(size_t)row * N + col] = __hip_bfloat16(acc[i][j][r]);
            }
    }
}

// -------- fused attn + proj GEMM: out = softmax-band(qkv) @ wprojT + bias --------
// grid (bn=8, bm=64), 512 threads = 8 waves (2x4). tile 64 rows x 128 cols.
// BK=128 = 2 heads per K-step: attn A-tile computed in-block into LDS.
__global__ __launch_bounds__(512) void attn_gemm2(
    const __hip_bfloat16* __restrict__ qkv,   // (B*T, 3*DIM): [q | k | v]
    const __hip_bfloat16* __restrict__ Bt,    // wprojT (1024 x 1024)
    const float* __restrict__ bias,
    float* __restrict__ C)                    // (B*T, DIM) fp32
{
    __shared__ __align__(16) __hip_bfloat16 As2[4][64][32];    // 16 KiB
    __shared__ __align__(16) __hip_bfloat16 Bs2[4][128][32];   // 32 KiB

    const int tid  = threadIdx.x;
    const int wv   = tid >> 6;
    const int lane = tid & 63;
    const int bn   = blockIdx.x;        // 0..7  (128 out cols)
    const int bm   = blockIdx.y;        // 0..63 (64 rows)
    const int wm   = wv >> 2, wn = wv & 3;

    // attn lane geometry: row in tile, 16-dim chunk
    const int arow = tid >> 3;          // 0..63
    const int g8   = tid & 7;           // chunk: dims [g8*16, g8*16+16) of K-step
    const int r    = bm * 64 + arow;    // global token
    const int t    = r & (T_SEQ - 1);
    const __hip_bfloat16* qrow = qkv + (size_t)r * (3 * DIMSZ);

    // B staging geometry (512 threads: one 16B issue per kh)
    const int srow = tid >> 2;          // 0..127
    const int scol = (tid & 3) * 8;

    const __hip_bfloat16* Bg = Bt + (size_t)(bn * 128) * DIMSZ;

    const int fm = lane & 15;
    const int fq = (lane >> 4) * 8;

    f32x4 acc[2][2] = {};

    const bool ok1 = (t + 1) < T_SEQ;
    const bool ok2 = (t + 2) < T_SEQ;
    const size_t roff1 = ok1 ? (size_t)(3 * DIMSZ) : 0;
    const size_t roff2 = ok2 ? (size_t)(6 * DIMSZ) : 0;

    for (int kk = 0; kk < DIMSZ; kk += 128) {
        // ---- B-stage: 128 x 128 k-slab via DMA ----
#pragma unroll
        for (int kh = 0; kh < 4; ++kh)
            gld_lds16(Bg + (size_t)srow * DIMSZ + kk + kh * 32 + scol,
                      &Bs2[kh][srow][scol]);

        // ---- attn for dims [kk + g8*16, +16) of row r (one head per 4 chunks) ----
        const int d0 = kk + g8 * 16;
        bf16x8 qa = *(const bf16x8*)(qrow + d0);
        bf16x8 qb = *(const bf16x8*)(qrow + d0 + 8);
        bf16x8 ka[3], kb[3], va[3], vb[3];
        {
            const __hip_bfloat16* k0 = qrow + DIMSZ + d0;
            const __hip_bfloat16* v0 = qrow + 2 * DIMSZ + d0;
            ka[0] = *(const bf16x8*)(k0);            kb[0] = *(const bf16x8*)(k0 + 8);
            va[0] = *(const bf16x8*)(v0);            vb[0] = *(const bf16x8*)(v0 + 8);
            ka[1] = *(const bf16x8*)(k0 + roff1);    kb[1] = *(const bf16x8*)(k0 + roff1 + 8);
            va[1] = *(const bf16x8*)(v0 + roff1);    vb[1] = *(const bf16x8*)(v0 + roff1 + 8);
            ka[2] = *(const bf16x8*)(k0 + roff2);    kb[2] = *(const bf16x8*)(k0 + roff2 + 8);
            va[2] = *(const bf16x8*)(v0 + roff2);    vb[2] = *(const bf16x8*)(v0 + roff2 + 8);
        }
        float qf[16];
#pragma unroll
        for (int i = 0; i < 8; ++i) {
            qf[i]     = bf2f((unsigned short)qa[i]);
            qf[i + 8] = bf2f((unsigned short)qb[i]);
        }
        float s[3];
#pragma unroll
        for (int j = 0; j < 3; ++j) {
            float d = 0.f;
#pragma unroll
            for (int i = 0; i < 8; ++i) {
                d += qf[i]     * bf2f((unsigned short)ka[j][i]);
                d += qf[i + 8] * bf2f((unsigned short)kb[j][i]);
            }
            // head = 64 dims = 4 chunks: reduce over g8 bits {0,1} (same row, same head)
            d += __shfl_xor(d, 1, 64);
            d += __shfl_xor(d, 2, 64);
            s[j] = d * 0.125f;
        }
        if (!ok1) s[1] = -1e30f;
        if (!ok2) s[2] = -1e30f;
        float m  = fmaxf(s[0], fmaxf(s[1], s[2]));
        float p0 = __expf(s[0] - m), p1 = __expf(s[1] - m), p2 = __expf(s[2] - m);
        float inv = 1.0f / (p0 + p1 + p2);
        union { __hip_bfloat16 h[8]; bf16x8 u; } w0, w1;
#pragma unroll
        for (int i = 0; i < 8; ++i) {
            float oa = p0 * bf2f((unsigned short)va[0][i])
                     + p1 * bf2f((unsigned short)va[1][i])
                     + p2 * bf2f((unsigned short)va[2][i]);
            float ob = p0 * bf2f((unsigned short)vb[0][i])
                     + p1 * bf2f((unsigned short)vb[1][i])
                     + p2 * bf2f((unsigned short)vb[2][i]);
            w0.h[i] = __hip_bfloat16(oa * inv);
            w1.h[i] = __hip_bfloat16(ob * inv);
        }
        // dims g8*16..+16 -> kh = g8>>1, col0 = (g8&1)*16
        {
            const int kh = g8 >> 1, c0 = (g8 & 1) * 16;
            *(bf16x8*)&As2[kh][arow][c0]     = w0.u;
            *(bf16x8*)&As2[kh][arow][c0 + 8] = w1.u;
        }
        __syncthreads();

        // ---- MFMA: 2x2 frags per wave over 4 kh sub-tiles ----
#pragma unroll
        for (int kh = 0; kh < 4; ++kh) {
            bf16x8 af[2], bfr[2];
#pragma unroll
            for (int i = 0; i < 2; ++i)
                af[i] = *(const bf16x8*)&As2[kh][wm * 32 + i * 16 + fm][fq];
#pragma unroll
            for (int j = 0; j < 2; ++j)
                bfr[j] = *(const bf16x8*)&Bs2[kh][wn * 32 + j * 16 + fm][fq];
#pragma unroll
            for (int i = 0; i < 2; ++i)
#pragma unroll
                for (int j = 0; j < 2; ++j)
                    acc[i][j] = __builtin_amdgcn_mfma_f32_16x16x32_bf16(af[i], bfr[j], acc[i][j], 0, 0, 0);
        }
        __syncthreads();
    }

    // epilogue: bias + fp32 store. C/D layout: col=lane&15, row=(lane>>4)*4+reg
    const int fcol  = lane & 15;
    const int frow4 = (lane >> 4) * 4;
    const int cm0 = bm * 64 + wm * 32;
    const int cn0 = bn * 128 + wn * 32;
#pragma unroll
    for (int j = 0; j < 2; ++j) {
        int col = cn0 + j * 16 + fcol;
        float bv = bias[col];
#pragma unroll
        for (int i = 0; i < 2; ++i)
#pragma unroll
            for (int rr = 0; rr < 4; ++rr) {
                int row = cm0 + i * 16 + frow4 + rr;
                C[(size_t)row * DIMSZ + col] = acc[i][j][rr] + bv;
            }
    }
}

extern "C" void kernel_launch(void* const* d_in, const int* in_sizes, int n_in,
                              void* d_out, int out_size, void* d_ws, size_t ws_size,
                              hipStream_t stream) {
    const float* x      = (const float*)d_in[0];  // (B,T,DIM) fp32
    const float* w_qkv  = (const float*)d_in[1];  // (DIM, 3*DIM) fp32
    const float* w_proj = (const float*)d_in[2];  // (DIM, DIM) fp32
    const float* b_proj = (const float*)d_in[3];  // (DIM,) fp32
    float* out = (float*)d_out;                   // (B,T,DIM) fp32

    const int M = NBATCH * T_SEQ;   // 4096

    // workspace (bf16 intermediates):
    //   [0,8M)    xb (x bf16)
    //   [8M,14M)  wqkvT  (3072x1024)
    //   [14M,16M) wprojT (1024x1024)
    //   [16M,40M) qkv    (4096x3072)
    char* ws = (char*)d_ws;
    __hip_bfloat16* xb     = (__hip_bfloat16*)(ws);
    __hip_bfloat16* wqkvT  = (__hip_bfloat16*)(ws + (8u  << 20));
    __hip_bfloat16* wprojT = (__hip_bfloat16*)(ws + (14u << 20));
    __hip_bfloat16* qkv    = (__hip_bfloat16*)(ws + (16u << 20));

    // 1) fused prep: x->bf16, both weight convert+transposes (64x64 tiles)
    prep<<<5120, 256, 0, stream>>>(x, xb, w_qkv, wqkvT, w_proj, wprojT);

    // 2) qkv = x @ w_qkv   (4096 x 3072, K=1024): 24x32=768 blocks = 3/CU
    gemm_bt_128<<<dim3(3 * DIMSZ / 128, M / 128), 256, 0, stream>>>(
        xb, wqkvT, qkv, M, 3 * DIMSZ, DIMSZ);

    // 3) fused banded-attn + out-proj + bias (one launch replaces two)
    attn_gemm2<<<dim3(DIMSZ / 128, M / 64), 512, 0, stream>>>(
        qkv, wprojT, b_proj, out);
}

// Round 8
// 138.817 us; speedup vs baseline: 1.1094x; 1.1094x over previous
//
#include <hip/hip_runtime.h>
#include <hip/hip_bf16.h>
#include <cstdint>
#include <cstddef>

// StreamingAttentionBlock: B=2, T=2048, DIM=1024, H=16, hd=64, window=3 keys
// I/O: fp32. Internal: bf16 MFMA, fp32 accumulation.
// R17 = R15 (141.4us best) + T1 bijective XCD swizzle on both GEMMs (1-D grid,
// chunk-per-XCD, bm-major decode). Mechanism: per-K-step vmcnt(0) drain length
// = tail load latency; per-XCD contiguous bm-chunks make the A-panel working
// set L2-resident (GEMM1: 1MB/XCD vs 8MB scattered; GEMM2: 1MB) -> L3-latency
// tail loads become L2 hits -> shorter drains. 768%8==0, 512%8==0 (bijective).
// R16 post-mortem: attn-into-GEMM2 fusion regressed +12.6us — the x8-redundant
// attn VALU chain sits SERIALLY inside every K-step between stage and MFMA;
// m114 overlap applies across waves' independent work, not barrier-gated phases.
// Separate attn (fully parallel, one pass) is strictly better. Reverted.
#define T_SEQ 2048
#define NBATCH 2
#define DIMSZ 1024
#define NHEAD 16
#define HDIM 64

typedef float f32x4 __attribute__((ext_vector_type(4)));
typedef short bf16x8 __attribute__((ext_vector_type(8)));

// async global->LDS, 16B per lane. LDS dest = wave-uniform base + lane*16.
__device__ __forceinline__ void gld_lds16(const __hip_bfloat16* g, __hip_bfloat16* l) {
    __builtin_amdgcn_global_load_lds(
        (const __attribute__((address_space(1))) unsigned int*)g,
        (__attribute__((address_space(3))) unsigned int*)l,
        16, 0, 0);
}

__device__ __forceinline__ float bf2f(unsigned short u) {
    union { unsigned int i; float f; } c; c.i = (unsigned int)u << 16; return c.f;
}

// -------- fused prep: convert x -> bf16; convert+transpose both weights --------
// grid: [0,4096) x-convert | [4096,4864) wqkv 64x64 tiles | [4864,5120) wproj
__global__ __launch_bounds__(256) void prep(
    const float* __restrict__ x,      __hip_bfloat16* __restrict__ xb,
    const float* __restrict__ wqkv,   __hip_bfloat16* __restrict__ wqkvT,
    const float* __restrict__ wproj,  __hip_bfloat16* __restrict__ wprojT)
{
    __shared__ float tile[64][65];
    const int b = blockIdx.x;
    if (b < 4096) {
        int i = (b * 256 + threadIdx.x) * 4;
        float4 v = *(const float4*)(x + i);
        union { __hip_bfloat16 h[4]; ushort4 u; } pk;
        pk.h[0] = __hip_bfloat16(v.x); pk.h[1] = __hip_bfloat16(v.y);
        pk.h[2] = __hip_bfloat16(v.z); pk.h[3] = __hip_bfloat16(v.w);
        *(ushort4*)(xb + i) = pk.u;
        return;
    }
    const float* in; __hip_bfloat16* out; int C, c0, r0;
    if (b < 4864) {
        int bb = b - 4096; in = wqkv; out = wqkvT; C = 3072;
        c0 = (bb % 48) * 64; r0 = (bb / 48) * 64;
    } else {
        int bb = b - 4864; in = wproj; out = wprojT; C = 1024;
        c0 = (bb & 15) * 64; r0 = (bb >> 4) * 64;
    }
    const int tx = threadIdx.x & 63, ty = threadIdx.x >> 6;   // 64 lanes x 4 rows
#pragma unroll
    for (int p = 0; p < 16; ++p) {
        int row = ty + p * 4;
        tile[row][tx] = in[(size_t)(r0 + row) * C + c0 + tx];
    }
    __syncthreads();
#pragma unroll
    for (int p = 0; p < 16; ++p) {
        int orow = ty + p * 4;   // out row = c0+orow; out col = r0+tx
        out[(size_t)(c0 + orow) * 1024 + r0 + tx] = __hip_bfloat16(tile[tx][orow]);
    }
}

// -------- GEMM1: 128x128 tile, BK=64, m97 staging; 1-D grid + XCD swizzle --------
__global__ __launch_bounds__(256) void gemm_bt_128(
    const __hip_bfloat16* __restrict__ A,
    const __hip_bfloat16* __restrict__ Bt,
    __hip_bfloat16* __restrict__ C,
    int M, int N, int K)
{
    __shared__ __align__(16) __hip_bfloat16 As[2 * 128 * 32];
    __shared__ __align__(16) __hip_bfloat16 Bs[2 * 128 * 32];

    const int tid  = threadIdx.x;
    const int wv   = tid >> 6;
    const int lane = tid & 63;

    // bijective XCD swizzle (gridDim.x % 8 == 0): each XCD gets a contiguous
    // bm-major chunk -> A-panel working set L2-resident (4 panels = 1 MB).
    const int cpx = gridDim.x >> 3;
    const int swb = (blockIdx.x & 7) * cpx + (blockIdx.x >> 3);
    const int nbn = N >> 7;
    const int bm = swb / nbn, bn = swb % nbn;

    const int wm   = wv >> 1, wn = wv & 1;

    f32x4 acc[4][4] = {};

    const int srow = lane >> 2;          // 0..15
    const int scol = (lane & 3) * 8;     // 16B per lane

    const __hip_bfloat16* Ag = A  + (size_t)(bm * 128) * K;
    const __hip_bfloat16* Bg = Bt + (size_t)(bn * 128) * K;

    const int fm = lane & 15;
    const int fq = (lane >> 4) * 8;

    for (int kk = 0; kk < K; kk += 64) {
#pragma unroll
        for (int kh = 0; kh < 2; ++kh)
#pragma unroll
            for (int it = 0; it < 2; ++it) {
                int row = (it * 4 + wv) * 16 + srow;          // 0..127
                gld_lds16(Ag + (size_t)row * K + kk + kh * 32 + scol,
                          As + kh * 4096 + row * 32 + scol);
                gld_lds16(Bg + (size_t)row * K + kk + kh * 32 + scol,
                          Bs + kh * 4096 + row * 32 + scol);
            }
        __syncthreads();

#pragma unroll
        for (int kh = 0; kh < 2; ++kh) {
            bf16x8 af[4], bfr[4];
#pragma unroll
            for (int i = 0; i < 4; ++i)
                af[i] = *(const bf16x8*)(As + kh * 4096 + (wm * 64 + i * 16 + fm) * 32 + fq);
#pragma unroll
            for (int j = 0; j < 4; ++j)
                bfr[j] = *(const bf16x8*)(Bs + kh * 4096 + (wn * 64 + j * 16 + fm) * 32 + fq);
#pragma unroll
            for (int i = 0; i < 4; ++i)
#pragma unroll
                for (int j = 0; j < 4; ++j)
                    acc[i][j] = __builtin_amdgcn_mfma_f32_16x16x32_bf16(af[i], bfr[j], acc[i][j], 0, 0, 0);
        }
        __syncthreads();
    }

    // C/D layout: col=lane&15, row=(lane>>4)*4+reg  [m89-verified]
    const int fcol  = lane & 15;
    const int frow4 = (lane >> 4) * 4;
    const int cm0 = bm * 128 + wm * 64;
    const int cn0 = bn * 128 + wn * 64;
#pragma unroll
    for (int j = 0; j < 4; ++j) {
        int col = cn0 + j * 16 + fcol;
#pragma unroll
        for (int i = 0; i < 4; ++i)
#pragma unroll
            for (int r = 0; r < 4; ++r) {
                int row = cm0 + i * 16 + frow4 + r;
                C[(size_t)row * N + col] = __hip_bfloat16(acc[i][j][r]);
            }
    }
}

// -------- GEMM2: 64x128 tile, BK=128; 1-D grid + XCD swizzle, fp32 out + bias --------
__global__ __launch_bounds__(256, 2) void gemm_bt_64(
    const __hip_bfloat16* __restrict__ A,
    const __hip_bfloat16* __restrict__ Bt,
    const float* __restrict__ bias,
    float* __restrict__ C,
    int M, int N, int K)
{
    __shared__ __align__(16) __hip_bfloat16 As2[4 * 64 * 32];    // 16 KiB
    __shared__ __align__(16) __hip_bfloat16 Bs2[4 * 128 * 32];   // 32 KiB

    const int tid  = threadIdx.x;
    const int wv   = tid >> 6;
    const int lane = tid & 63;

    // bijective XCD swizzle (gridDim.x % 8 == 0), bm-major decode
    const int cpx = gridDim.x >> 3;
    const int swb = (blockIdx.x & 7) * cpx + (blockIdx.x >> 3);
    const int nbn = N >> 7;
    const int bm = swb / nbn, bn = swb % nbn;

    const int wm   = wv >> 1, wn = wv & 1;

    f32x4 acc[2][4] = {};

    const int srow = lane >> 2;
    const int scol = (lane & 3) * 8;

    const __hip_bfloat16* Ag = A  + (size_t)(bm * 64) * K;
    const __hip_bfloat16* Bg = Bt + (size_t)(bn * 128) * K;

    const int fm = lane & 15;
    const int fq = (lane >> 4) * 8;

    for (int kk = 0; kk < K; kk += 128) {
#pragma unroll
        for (int kh = 0; kh < 4; ++kh) {
            {
                int row = wv * 16 + srow;                     // 0..63
                gld_lds16(Ag + (size_t)row * K + kk + kh * 32 + scol,
                          As2 + kh * 2048 + row * 32 + scol);
            }
#pragma unroll
            for (int it = 0; it < 2; ++it) {
                int row = (it * 4 + wv) * 16 + srow;          // 0..127
                gld_lds16(Bg + (size_t)row * K + kk + kh * 32 + scol,
                          Bs2 + kh * 4096 + row * 32 + scol);
            }
        }
        __syncthreads();

#pragma unroll
        for (int kh = 0; kh < 4; ++kh) {
            bf16x8 af[2], bfr[4];
#pragma unroll
            for (int i = 0; i < 2; ++i)
                af[i] = *(const bf16x8*)(As2 + kh * 2048 + (wm * 32 + i * 16 + fm) * 32 + fq);
#pragma unroll
            for (int j = 0; j < 4; ++j)
                bfr[j] = *(const bf16x8*)(Bs2 + kh * 4096 + (wn * 64 + j * 16 + fm) * 32 + fq);
#pragma unroll
            for (int i = 0; i < 2; ++i)
#pragma unroll
                for (int j = 0; j < 4; ++j)
                    acc[i][j] = __builtin_amdgcn_mfma_f32_16x16x32_bf16(af[i], bfr[j], acc[i][j], 0, 0, 0);
        }
        __syncthreads();
    }

    const int fcol  = lane & 15;
    const int frow4 = (lane >> 4) * 4;
    const int cm0 = bm * 64 + wm * 32;
    const int cn0 = bn * 128 + wn * 64;
#pragma unroll
    for (int j = 0; j < 4; ++j) {
        int col = cn0 + j * 16 + fcol;
        float bv = bias[col];
#pragma unroll
        for (int i = 0; i < 2; ++i)
#pragma unroll
            for (int r = 0; r < 4; ++r) {
                int row = cm0 + i * 16 + frow4 + r;
                C[(size_t)row * N + col] = acc[i][j][r] + bv;
            }
    }
}

// -------- banded attention: 2 tokens/block, thread = 8-dim chunk, 16B loads --------
__global__ __launch_bounds__(256) void attn_banded(
    const __hip_bfloat16* __restrict__ qkv,   // (B*T, 3*DIM): [q | k | v]
    __hip_bfloat16* __restrict__ o)           // (B*T, DIM)
{
    const int tid = threadIdx.x;
    const int t8  = tid & 127;           // dim-chunk: dims [8*t8, 8*t8+8)
    const int r   = blockIdx.x * 2 + (tid >> 7);   // b*T + t
    const int t   = r & (T_SEQ - 1);
    const size_t rb = (size_t)r * (3 * DIMSZ);
    const int d0 = t8 * 8;

    bf16x8 qu = *(const bf16x8*)(qkv + rb + d0);
    float q[8];
#pragma unroll
    for (int i = 0; i < 8; ++i) q[i] = bf2f((unsigned short)qu[i]);

    float s[3], vv[3][8];
#pragma unroll
    for (int j = 0; j < 3; ++j) {
        bool ok = (t + j) < T_SEQ;       // masks seq end (and batch boundary)
        size_t rbj = ok ? rb + (size_t)j * (3 * DIMSZ) : rb;
        bf16x8 ku = *(const bf16x8*)(qkv + rbj + DIMSZ + d0);
        bf16x8 vu = *(const bf16x8*)(qkv + rbj + 2 * DIMSZ + d0);
        float d = 0.f;
#pragma unroll
        for (int i = 0; i < 8; ++i) {
            vv[j][i] = bf2f((unsigned short)vu[i]);
            d += q[i] * bf2f((unsigned short)ku[i]);
        }
        // head = 64 dims = 8 lanes x 8 dims: reduce within aligned 8-lane group
        d += __shfl_xor(d, 4, 64);
        d += __shfl_xor(d, 2, 64);
        d += __shfl_xor(d, 1, 64);
        s[j] = ok ? d * 0.125f : -1e30f; // scale = 64^-0.5
    }
    float m  = fmaxf(s[0], fmaxf(s[1], s[2]));
    float p0 = __expf(s[0] - m), p1 = __expf(s[1] - m), p2 = __expf(s[2] - m);
    float inv = 1.0f / (p0 + p1 + p2);
    union { __hip_bfloat16 h[8]; bf16x8 u; } pk;
#pragma unroll
    for (int i = 0; i < 8; ++i)
        pk.h[i] = __hip_bfloat16((p0 * vv[0][i] + p1 * vv[1][i] + p2 * vv[2][i]) * inv);
    *(bf16x8*)(o + (size_t)r * DIMSZ + d0) = pk.u;
}

extern "C" void kernel_launch(void* const* d_in, const int* in_sizes, int n_in,
                              void* d_out, int out_size, void* d_ws, size_t ws_size,
                              hipStream_t stream) {
    const float* x      = (const float*)d_in[0];  // (B,T,DIM) fp32
    const float* w_qkv  = (const float*)d_in[1];  // (DIM, 3*DIM) fp32
    const float* w_proj = (const float*)d_in[2];  // (DIM, DIM) fp32
    const float* b_proj = (const float*)d_in[3];  // (DIM,) fp32
    float* out = (float*)d_out;                   // (B,T,DIM) fp32

    const int M = NBATCH * T_SEQ;   // 4096

    // workspace (bf16 intermediates):
    //   [0,8M)    xb (x bf16) -> reused as attn output after GEMM1 consumes it
    //   [8M,14M)  wqkvT  (3072x1024)
    //   [14M,16M) wprojT (1024x1024)
    //   [16M,40M) qkv    (4096x3072)
    char* ws = (char*)d_ws;
    __hip_bfloat16* xb     = (__hip_bfloat16*)(ws);
    __hip_bfloat16* attn   = (__hip_bfloat16*)(ws);            // reuse of xb region
    __hip_bfloat16* wqkvT  = (__hip_bfloat16*)(ws + (8u  << 20));
    __hip_bfloat16* wprojT = (__hip_bfloat16*)(ws + (14u << 20));
    __hip_bfloat16* qkv    = (__hip_bfloat16*)(ws + (16u << 20));

    // 1) fused prep: x->bf16, both weight convert+transposes (64x64 tiles)
    prep<<<5120, 256, 0, stream>>>(x, xb, w_qkv, wqkvT, w_proj, wprojT);

    // 2) qkv = x @ w_qkv (4096 x 3072, K=1024): 768 blocks, XCD-swizzled
    gemm_bt_128<<<(M / 128) * (3 * DIMSZ / 128), 256, 0, stream>>>(
        xb, wqkvT, qkv, M, 3 * DIMSZ, DIMSZ);

    // 3) banded attention (3-key window) -> bf16 attn (reuses xb region)
    attn_banded<<<M / 2, 256, 0, stream>>>(qkv, attn);

    // 4) out = attn @ w_proj + b_proj (4096 x 1024): 512 blocks, XCD-swizzled
    gemm_bt_64<<<(M / 64) * (DIMSZ / 128), 256, 0, stream>>>(
        attn, wprojT, b_proj, out, M, DIMSZ, DIMSZ);
}